// Round 4
// baseline (617.774 us; speedup 1.0000x reference)
//
#include <hip/hip_runtime.h>

// Problem constants (from reference setup_inputs)
#define B_    2048
#define N_    64
#define E_    512
#define K_    20
#define C_    6      // self classes; neighbor classes = C_+1
#define DSELF 120    // IN*(OBS+PRED) = 6*20
#define DNEI  48     // IN*OBS = 6*8
#define DPRED 72     // IN*PRED = 6*12
#define EPS_  1e-4f

// workspace layout: [const2: C_*K_*E_ floats][nt: B_*N_*DNEI floats]
#define C2_ELEMS ((size_t)C_ * K_ * E_)            // 61440
#define NT_ELEMS ((size_t)B_ * N_ * DNEI)          // 6291456
#define WS_NEED  ((C2_ELEMS + NT_ELEMS) * sizeof(float))   // 25,411,584 B

#define TBLOCKS 1536                               // transform part of prep
// NT float4 count = 6291456/4 = 1572864 = 1536*256*4 exactly

// ---------------------------------------------------------------------------
// prep: (a) blocks [0,120): const2[c,k,e] = b_self[c,e] + it[c,k,:]·W_self[c,48:,e]
//           (the b-independent part of the self embedding; 88 MFLOP total)
//       (b) blocks [120,1656): nt = signed-reciprocal(neis) streamed to d_ws
//           so the nei GEMM can read rows through uniform scalar-cache loads.
// Bounds audit (r3): part(a) max W_self float idx 368,639 < 6*120*512;
// part(b) max idx = NT float4 count exactly; ws writes end at WS_NEED.
// ---------------------------------------------------------------------------
__global__ __launch_bounds__(256) void prep(
    const float* __restrict__ neis,        // [B,64,48]
    const float* __restrict__ init_trajs,  // [C,K,72]
    const float* __restrict__ W_self,      // [C,120,512]
    const float* __restrict__ b_self,      // [C,512]
    float*       __restrict__ ws)          // [const2 | nt]
{
    const int tid = threadIdx.x;
    const int bid = blockIdx.x;
    if (bid < C_ * K_) {
        const int c = bid / K_;
        // it row: uniform address -> scalar loads; shared by all 256 threads
        const float* itr = init_trajs + (size_t)bid * DPRED;
        const float2* Wp = reinterpret_cast<const float2*>(
                               W_self + ((size_t)c * DSELF + DNEI) * E_) + tid;
        float2 acc = reinterpret_cast<const float2*>(b_self + (size_t)c * E_)[tid];
        #pragma unroll
        for (int j = 0; j < DPRED; ++j) {
            const float t  = itr[j];                 // wave-uniform
            const float2 w = Wp[(size_t)j * (E_ / 2)];
            acc.x += t * w.x; acc.y += t * w.y;
        }
        reinterpret_cast<float2*>(ws + (size_t)bid * E_)[tid] = acc;
    } else {
        const int ib = bid - C_ * K_;
        const size_t base   = (size_t)ib * 256 + tid;
        const size_t stride = (size_t)TBLOCKS * 256;
        const float4* in4 = reinterpret_cast<const float4*>(neis);
        float4* o4 = reinterpret_cast<float4*>(ws + C2_ELEMS);
        #pragma unroll
        for (int t = 0; t < 4; ++t) {
            const size_t idx = base + (size_t)t * stride;
            const float4 v = in4[idx];
            float4 o;
            o.x = (v.x >= 0.f) ? 1.f / (v.x + EPS_) : 1.f / (v.x - EPS_);
            o.y = (v.y >= 0.f) ? 1.f / (v.y + EPS_) : 1.f / (v.y - EPS_);
            o.z = (v.z >= 0.f) ? 1.f / (v.z + EPS_) : 1.f / (v.z - EPS_);
            o.w = (v.w >= 0.f) ? 1.f / (v.w + EPS_) : 1.f / (v.w - EPS_);
            o4[idx] = o;
        }
    }
}

// ---------------------------------------------------------------------------
// self_fast: x[b,k,e] = obs[b,:48]·W_self[c,:48,e]  +  const2[c,k,e]
// GEMV (96 FMA/thread) then broadcast-add + store. Write-bound (~84 MB).
// obs row read via uniform-address loads; W float2 loads coalesced + L2-hot.
// ---------------------------------------------------------------------------
__global__ __launch_bounds__(256) void self_fast(
    const float* __restrict__ obs,      // [B,48]
    const float* __restrict__ W_self,   // [C,120,512]
    const int*   __restrict__ labels,   // [B]
    const float* __restrict__ c2,       // [C,K,512] (ws)
    float*       __restrict__ out)      // [B,K,512]
{
    const int b   = blockIdx.x;
    const int tid = threadIdx.x;
    const int c   = labels[b];

    const float*  ob = obs + (size_t)b * DNEI;
    const float2* Wp = reinterpret_cast<const float2*>(
                           W_self + (size_t)c * DSELF * E_) + tid;
    float ax = 0.f, ay = 0.f;
    #pragma unroll
    for (int j = 0; j < DNEI; ++j) {
        const float t  = ob[j];                      // wave-uniform
        const float2 w = Wp[(size_t)j * (E_ / 2)];
        ax += t * w.x; ay += t * w.y;
    }

    const float2* cp = reinterpret_cast<const float2*>(
                           c2 + (size_t)c * K_ * E_) + tid;
    float2* op = reinterpret_cast<float2*>(out + (size_t)b * K_ * E_) + tid;
    #pragma unroll
    for (int k = 0; k < K_; ++k) {
        const float2 v = cp[(size_t)k * (E_ / 2)];
        float2 o; o.x = ax + v.x; o.y = ay + v.y;
        op[(size_t)k * (E_ / 2)] = o;
    }
}

// ---------------------------------------------------------------------------
// nei_gemm: identical control flow to the VERIFIED fallback (per-class W
// register-cache + block-uniform `if (lab[n] != c) continue` row sweep), but
// the row operand comes from the pre-transformed nt in workspace through a
// FULLY UNIFORM global address (blockIdx + loop counter -> compiler emits
// scalar loads). Zero LDS data traffic -> removes the LDS broadcast-read
// bottleneck of the old kernel (~12 cyc/b128 x 768 instr/wave of CU-shared
// LDS pipe time).
// ---------------------------------------------------------------------------
__global__ __launch_bounds__(256) void nei_gemm(
    const float* __restrict__ nts,     // [B,64,48] transformed (ws)
    const float* __restrict__ W_nei,   // [C+1,48,512]
    const float* __restrict__ b_nei,   // [C+1,512]
    const int*   __restrict__ labels,  // [B,64]
    float*       __restrict__ out)     // [B,64,512]
{
    const int b   = blockIdx.x;
    const int tid = threadIdx.x;

    __shared__ int lab[N_];
    if (tid < N_) lab[tid] = labels[b * N_ + tid];
    __syncthreads();

    float wl[DNEI], wh[DNEI];

    for (int c = 0; c < C_ + 1; ++c) {
        const float2* Wp = reinterpret_cast<const float2*>(
                               W_nei + (size_t)c * DNEI * E_) + tid;
        #pragma unroll
        for (int j = 0; j < DNEI; ++j) {
            const float2 w = Wp[(size_t)j * (E_ / 2)];
            wl[j] = w.x;
            wh[j] = w.y;
        }
        const float2 bs = reinterpret_cast<const float2*>(
                              b_nei + (size_t)c * E_)[tid];

        for (int n = 0; n < N_; ++n) {
            if (lab[n] != c) continue;   // block-uniform branch
            // row pointer is provably uniform: blockIdx + loop counter only
            const float* r = nts + ((size_t)b * N_ + n) * DNEI;
            float a0 = bs.x, a1 = bs.y;
            #pragma unroll
            for (int j = 0; j < DNEI; ++j) {
                const float t = r[j];    // uniform -> scalar-cache load
                a0 += t * wl[j];
                a1 += t * wh[j];
            }
            float2 o; o.x = a0; o.y = a1;
            reinterpret_cast<float2*>(out + ((size_t)b * N_ + n) * E_)[tid] = o;
        }
    }
}

// ---------------------------------------------------------------------------
// Fallback kernels (round-0 verified version, 555 µs) — used only if d_ws is
// too small for the const2 + nt staging (needs ~25.4 MB).
// ---------------------------------------------------------------------------
__global__ __launch_bounds__(256) void self_embed_fb(
    const float* __restrict__ obs,
    const float* __restrict__ init_trajs,
    const float* __restrict__ W_self,
    const float* __restrict__ b_self,
    const int*   __restrict__ labels,
    float*       __restrict__ out)
{
    const int b   = blockIdx.x;
    const int tid = threadIdx.x;
    const int c   = labels[b];

    __shared__ __align__(16) float traj[DSELF * K_];

    for (int idx = tid; idx < DSELF * K_; idx += 256) {
        const int j = idx / K_;
        const int k = idx - j * K_;
        float v;
        if (j < DNEI) v = obs[b * DNEI + j];
        else          v = init_trajs[(c * K_ + k) * DPRED + (j - DNEI)];
        traj[idx] = v;
    }
    __syncthreads();

    float acc[K_][2];
    #pragma unroll
    for (int k = 0; k < K_; ++k) { acc[k][0] = 0.f; acc[k][1] = 0.f; }

    const float2* Wp = reinterpret_cast<const float2*>(W_self + (size_t)c * DSELF * E_) + tid;

    for (int j = 0; j < DSELF; ++j) {
        const float2 w  = Wp[j * (E_ / 2)];
        const float4* tp = reinterpret_cast<const float4*>(&traj[j * K_]);
        #pragma unroll
        for (int q = 0; q < 5; ++q) {
            const float4 t4 = tp[q];
            acc[q * 4 + 0][0] += t4.x * w.x; acc[q * 4 + 0][1] += t4.x * w.y;
            acc[q * 4 + 1][0] += t4.y * w.x; acc[q * 4 + 1][1] += t4.y * w.y;
            acc[q * 4 + 2][0] += t4.z * w.x; acc[q * 4 + 2][1] += t4.z * w.y;
            acc[q * 4 + 3][0] += t4.w * w.x; acc[q * 4 + 3][1] += t4.w * w.y;
        }
    }

    const float2 bs = reinterpret_cast<const float2*>(b_self + c * E_)[tid];
    #pragma unroll
    for (int k = 0; k < K_; ++k) {
        float2 o;
        o.x = acc[k][0] + bs.x;
        o.y = acc[k][1] + bs.y;
        reinterpret_cast<float2*>(out + (size_t)(b * K_ + k) * E_)[tid] = o;
    }
}

__global__ __launch_bounds__(256) void nei_embed_fb(
    const float* __restrict__ neis,
    const float* __restrict__ W_nei,
    const float* __restrict__ b_nei,
    const int*   __restrict__ labels,
    float*       __restrict__ out)
{
    const int b   = blockIdx.x;
    const int tid = threadIdx.x;

    __shared__ __align__(16) float nt[N_ * DNEI];
    __shared__ int lab[N_];

    if (tid < N_) lab[tid] = labels[b * N_ + tid];

    const float4* np4 = reinterpret_cast<const float4*>(neis + (size_t)b * N_ * DNEI);
    float4* nt4 = reinterpret_cast<float4*>(nt);
    #pragma unroll
    for (int i = 0; i < 3; ++i) {
        const int idx = tid + i * 256;
        float4 v = np4[idx];
        float4 o;
        o.x = (v.x >= 0.f) ? 1.f / (v.x + EPS_) : 1.f / (v.x - EPS_);
        o.y = (v.y >= 0.f) ? 1.f / (v.y + EPS_) : 1.f / (v.y - EPS_);
        o.z = (v.z >= 0.f) ? 1.f / (v.z + EPS_) : 1.f / (v.z - EPS_);
        o.w = (v.w >= 0.f) ? 1.f / (v.w + EPS_) : 1.f / (v.w - EPS_);
        nt4[idx] = o;
    }
    __syncthreads();

    float wl[DNEI], wh[DNEI];

    for (int c = 0; c < C_ + 1; ++c) {
        const float2* Wp = reinterpret_cast<const float2*>(W_nei + (size_t)c * DNEI * E_) + tid;
        #pragma unroll
        for (int j = 0; j < DNEI; ++j) {
            const float2 w = Wp[j * (E_ / 2)];
            wl[j] = w.x;
            wh[j] = w.y;
        }
        const float2 bs = reinterpret_cast<const float2*>(b_nei + c * E_)[tid];

        for (int n = 0; n < N_; ++n) {
            if (lab[n] != c) continue;
            float a0 = bs.x, a1 = bs.y;
            const float4* tp = reinterpret_cast<const float4*>(&nt[n * DNEI]);
            #pragma unroll
            for (int q = 0; q < 12; ++q) {
                const float4 t4 = tp[q];
                a0 += t4.x * wl[q * 4 + 0]; a1 += t4.x * wh[q * 4 + 0];
                a0 += t4.y * wl[q * 4 + 1]; a1 += t4.y * wh[q * 4 + 1];
                a0 += t4.z * wl[q * 4 + 2]; a1 += t4.z * wh[q * 4 + 2];
                a0 += t4.w * wl[q * 4 + 3]; a1 += t4.w * wh[q * 4 + 3];
            }
            float2 o; o.x = a0; o.y = a1;
            reinterpret_cast<float2*>(out + (size_t)(b * N_ + n) * E_)[tid] = o;
        }
    }
}

extern "C" void kernel_launch(void* const* d_in, const int* in_sizes, int n_in,
                              void* d_out, int out_size, void* d_ws, size_t ws_size,
                              hipStream_t stream) {
    const float* obs  = (const float*)d_in[0];
    const float* neis = (const float*)d_in[1];
    const float* it   = (const float*)d_in[2];
    const float* Ws   = (const float*)d_in[3];
    const float* bs   = (const float*)d_in[4];
    const float* Wn   = (const float*)d_in[5];
    const float* bn   = (const float*)d_in[6];
    const int* sl = (const int*)d_in[7];
    const int* nl = (const int*)d_in[8];

    float* out_x = (float*)d_out;                        // [B,K,E]
    float* out_n = out_x + (size_t)B_ * K_ * E_;         // [B,N,E]

    if (d_ws != nullptr && ws_size >= WS_NEED) {
        float* c2 = (float*)d_ws;                        // [C,K,E]
        float* nt = c2 + C2_ELEMS;                       // [B,N,48]
        prep<<<dim3(C_ * K_ + TBLOCKS), dim3(256), 0, stream>>>(neis, it, Ws, bs, (float*)d_ws);
        self_fast<<<dim3(B_), dim3(256), 0, stream>>>(obs, Ws, sl, c2, out_x);
        nei_gemm<<<dim3(B_), dim3(256), 0, stream>>>(nt, Wn, bn, nl, out_n);
    } else {
        self_embed_fb<<<dim3(B_), dim3(256), 0, stream>>>(obs, it, Ws, bs, sl, out_x);
        nei_embed_fb<<<dim3(B_), dim3(256), 0, stream>>>(neis, Wn, bn, nl, out_n);
    }
}

// Round 5
// 570.009 us; speedup vs baseline: 1.0838x; 1.0838x over previous
//
#include <hip/hip_runtime.h>

// Problem constants (from reference setup_inputs)
#define B_    2048
#define N_    64
#define E_    512
#define K_    20
#define C_    6      // self classes; neighbor classes = C_+1
#define DSELF 120    // IN*(OBS+PRED) = 6*20
#define DNEI  48     // IN*OBS = 6*8
#define DPRED 72     // IN*PRED = 6*12
#define EPS_  1e-4f

// workspace layout: [const2: C_*K_*E_ floats]
#define C2_ELEMS ((size_t)C_ * K_ * E_)            // 61440
#define WS_NEED  (C2_ELEMS * sizeof(float))        // 245,760 B

// ---------------------------------------------------------------------------
// prep: const2[c,k,e] = b_self[c,e] + it[c,k,:]·W_self[c,48:,e]
// (the b-independent part of the self embedding; 88 MFLOP total, 120 blocks)
// ---------------------------------------------------------------------------
__global__ __launch_bounds__(256) void prep(
    const float* __restrict__ init_trajs,  // [C,K,72]
    const float* __restrict__ W_self,      // [C,120,512]
    const float* __restrict__ b_self,      // [C,512]
    float*       __restrict__ c2)          // [C,K,512]
{
    const int tid = threadIdx.x;
    const int bid = blockIdx.x;            // = c*K + k, grid = 120
    const int c = bid / K_;
    const float* itr = init_trajs + (size_t)bid * DPRED;   // uniform address
    const float2* Wp = reinterpret_cast<const float2*>(
                           W_self + ((size_t)c * DSELF + DNEI) * E_) + tid;
    float2 acc = reinterpret_cast<const float2*>(b_self + (size_t)c * E_)[tid];
    #pragma unroll
    for (int j = 0; j < DPRED; ++j) {
        const float t  = itr[j];                 // wave-uniform
        const float2 w = Wp[(size_t)j * (E_ / 2)];
        acc.x += t * w.x; acc.y += t * w.y;
    }
    reinterpret_cast<float2*>(c2 + (size_t)bid * E_)[tid] = acc;
}

// ---------------------------------------------------------------------------
// self_fast: x[b,k,e] = obs[b,:48]·W_self[c,:48,e]  +  const2[c,k,e]
// GEMV (96 FMA/thread) then broadcast-add + store. Write-bound (~84 MB).
// (unchanged from round 4 — was not the bottleneck)
// ---------------------------------------------------------------------------
__global__ __launch_bounds__(256) void self_fast(
    const float* __restrict__ obs,      // [B,48]
    const float* __restrict__ W_self,   // [C,120,512]
    const int*   __restrict__ labels,   // [B]
    const float* __restrict__ c2,       // [C,K,512] (ws)
    float*       __restrict__ out)      // [B,K,512]
{
    const int b   = blockIdx.x;
    const int tid = threadIdx.x;
    const int c   = labels[b];

    const float*  ob = obs + (size_t)b * DNEI;
    const float2* Wp = reinterpret_cast<const float2*>(
                           W_self + (size_t)c * DSELF * E_) + tid;
    float ax = 0.f, ay = 0.f;
    #pragma unroll
    for (int j = 0; j < DNEI; ++j) {
        const float t  = ob[j];                      // wave-uniform
        const float2 w = Wp[(size_t)j * (E_ / 2)];
        ax += t * w.x; ay += t * w.y;
    }

    const float2* cp = reinterpret_cast<const float2*>(
                           c2 + (size_t)c * K_ * E_) + tid;
    float2* op = reinterpret_cast<float2*>(out + (size_t)b * K_ * E_) + tid;
    #pragma unroll
    for (int k = 0; k < K_; ++k) {
        const float2 v = cp[(size_t)k * (E_ / 2)];
        float2 o; o.x = ax + v.x; o.y = ay + v.y;
        op[(size_t)k * (E_ / 2)] = o;
    }
}

// ---------------------------------------------------------------------------
// nei_rl: one block per b. Lane l holds the TRANSFORMED row l of this b in 48
// VGPRs (loaded coalesced from neis, signed-reciprocal applied inline — no
// staging pass, no LDS). Per class: W e-pair column register-cached (96 VGPR,
// same pattern as the verified fallback); per row n the 48 row values are
// broadcast with v_readlane_b32 (reg index j compile-time via full unroll,
// lane index n is a runtime SGPR — ISA-legal). Labels are also lane-held, so
// the class test is readlane -> pure scalar branch. Zero LDS data traffic,
// zero scalar-memory loads in the hot loop; VALU-bound by design:
// 64 rows x (48 readlane + 96 fmac) ~= 18.4k cyc/wave.
// ---------------------------------------------------------------------------
__global__ __launch_bounds__(256, 2) void nei_rl(
    const float* __restrict__ neis,    // [B,64,48]
    const float* __restrict__ W_nei,   // [C+1,48,512]
    const float* __restrict__ b_nei,   // [C+1,512]
    const int*   __restrict__ labels,  // [B,64]
    float*       __restrict__ out)     // [B,64,512]
{
    const int b    = blockIdx.x;
    const int tid  = threadIdx.x;
    const int lane = tid & 63;

    // --- my row (row `lane` of batch b), transformed, in registers ---
    float r[DNEI];
    {
        const float4* src = reinterpret_cast<const float4*>(
                                neis + (size_t)b * N_ * DNEI);
        #pragma unroll
        for (int i = 0; i < DNEI / 4; ++i) {
            const float4 v = src[lane * (DNEI / 4) + i];
            r[i * 4 + 0] = (v.x >= 0.f) ? 1.f / (v.x + EPS_) : 1.f / (v.x - EPS_);
            r[i * 4 + 1] = (v.y >= 0.f) ? 1.f / (v.y + EPS_) : 1.f / (v.y - EPS_);
            r[i * 4 + 2] = (v.z >= 0.f) ? 1.f / (v.z + EPS_) : 1.f / (v.z - EPS_);
            r[i * 4 + 3] = (v.w >= 0.f) ? 1.f / (v.w + EPS_) : 1.f / (v.w - EPS_);
        }
    }
    const int myLab = labels[b * N_ + lane];

    float wl[DNEI], wh[DNEI];

    for (int c = 0; c < C_ + 1; ++c) {
        const float2* Wp = reinterpret_cast<const float2*>(
                               W_nei + (size_t)c * DNEI * E_) + tid;
        #pragma unroll
        for (int j = 0; j < DNEI; ++j) {
            const float2 w = Wp[(size_t)j * (E_ / 2)];
            wl[j] = w.x;
            wh[j] = w.y;
        }
        const float2 bs = reinterpret_cast<const float2*>(
                              b_nei + (size_t)c * E_)[tid];

        for (int n = 0; n < N_; ++n) {
            const int labn = __builtin_amdgcn_readlane(myLab, n);  // SGPR
            if (labn != c) continue;     // scalar (wave-uniform) branch

            float a0 = bs.x, a1 = bs.y, a2 = 0.f, a3 = 0.f;
            #pragma unroll
            for (int j = 0; j < DNEI; j += 2) {
                const float t0 = __int_as_float(
                    __builtin_amdgcn_readlane(__float_as_int(r[j]), n));
                const float t1 = __int_as_float(
                    __builtin_amdgcn_readlane(__float_as_int(r[j + 1]), n));
                a0 += t0 * wl[j];     a1 += t0 * wh[j];
                a2 += t1 * wl[j + 1]; a3 += t1 * wh[j + 1];
            }
            float2 o; o.x = a0 + a2; o.y = a1 + a3;
            reinterpret_cast<float2*>(out + ((size_t)b * N_ + n) * E_)[tid] = o;
        }
    }
}

// ---------------------------------------------------------------------------
// Fallback for the self path (round-0 verified) — only if d_ws is too small
// for const2 (240 KB). nei_rl needs no workspace.
// ---------------------------------------------------------------------------
__global__ __launch_bounds__(256) void self_embed_fb(
    const float* __restrict__ obs,
    const float* __restrict__ init_trajs,
    const float* __restrict__ W_self,
    const float* __restrict__ b_self,
    const int*   __restrict__ labels,
    float*       __restrict__ out)
{
    const int b   = blockIdx.x;
    const int tid = threadIdx.x;
    const int c   = labels[b];

    __shared__ __align__(16) float traj[DSELF * K_];

    for (int idx = tid; idx < DSELF * K_; idx += 256) {
        const int j = idx / K_;
        const int k = idx - j * K_;
        float v;
        if (j < DNEI) v = obs[b * DNEI + j];
        else          v = init_trajs[(c * K_ + k) * DPRED + (j - DNEI)];
        traj[idx] = v;
    }
    __syncthreads();

    float acc[K_][2];
    #pragma unroll
    for (int k = 0; k < K_; ++k) { acc[k][0] = 0.f; acc[k][1] = 0.f; }

    const float2* Wp = reinterpret_cast<const float2*>(W_self + (size_t)c * DSELF * E_) + tid;

    for (int j = 0; j < DSELF; ++j) {
        const float2 w  = Wp[j * (E_ / 2)];
        const float4* tp = reinterpret_cast<const float4*>(&traj[j * K_]);
        #pragma unroll
        for (int q = 0; q < 5; ++q) {
            const float4 t4 = tp[q];
            acc[q * 4 + 0][0] += t4.x * w.x; acc[q * 4 + 0][1] += t4.x * w.y;
            acc[q * 4 + 1][0] += t4.y * w.x; acc[q * 4 + 1][1] += t4.y * w.y;
            acc[q * 4 + 2][0] += t4.z * w.x; acc[q * 4 + 2][1] += t4.z * w.y;
            acc[q * 4 + 3][0] += t4.w * w.x; acc[q * 4 + 3][1] += t4.w * w.y;
        }
    }

    const float2 bs = reinterpret_cast<const float2*>(b_self + c * E_)[tid];
    #pragma unroll
    for (int k = 0; k < K_; ++k) {
        float2 o;
        o.x = acc[k][0] + bs.x;
        o.y = acc[k][1] + bs.y;
        reinterpret_cast<float2*>(out + (size_t)(b * K_ + k) * E_)[tid] = o;
    }
}

extern "C" void kernel_launch(void* const* d_in, const int* in_sizes, int n_in,
                              void* d_out, int out_size, void* d_ws, size_t ws_size,
                              hipStream_t stream) {
    const float* obs  = (const float*)d_in[0];
    const float* neis = (const float*)d_in[1];
    const float* it   = (const float*)d_in[2];
    const float* Ws   = (const float*)d_in[3];
    const float* bs   = (const float*)d_in[4];
    const float* Wn   = (const float*)d_in[5];
    const float* bn   = (const float*)d_in[6];
    const int* sl = (const int*)d_in[7];
    const int* nl = (const int*)d_in[8];

    float* out_x = (float*)d_out;                        // [B,K,E]
    float* out_n = out_x + (size_t)B_ * K_ * E_;         // [B,N,E]

    // neighbor path: no workspace needed
    nei_rl<<<dim3(B_), dim3(256), 0, stream>>>(neis, Wn, bn, nl, out_n);

    // self path: const2 precompute in ws if available, else verified fallback
    if (d_ws != nullptr && ws_size >= WS_NEED) {
        float* c2 = (float*)d_ws;                        // [C,K,E]
        prep<<<dim3(C_ * K_), dim3(256), 0, stream>>>(it, Ws, bs, c2);
        self_fast<<<dim3(B_), dim3(256), 0, stream>>>(obs, Ws, sl, c2, out_x);
    } else {
        self_embed_fb<<<dim3(B_), dim3(256), 0, stream>>>(obs, it, Ws, bs, sl, out_x);
    }
}

// Round 6
// 567.361 us; speedup vs baseline: 1.0889x; 1.0047x over previous
//
#include <hip/hip_runtime.h>

// Problem constants (from reference setup_inputs)
#define B_    2048
#define N_    64
#define E_    512
#define K_    20
#define C_    6      // self classes; neighbor classes = C_+1
#define DSELF 120    // IN*(OBS+PRED) = 6*20
#define DNEI  48     // IN*OBS = 6*8
#define DPRED 72     // IN*PRED = 6*12
#define EPS_  1e-4f

// workspace layout: [const2: C_*K_*E_ floats]
#define C2_ELEMS ((size_t)C_ * K_ * E_)            // 61440
#define WS_NEED  (C2_ELEMS * sizeof(float))        // 245,760 B

#define TRF(x) (((x) >= 0.f) ? 1.f / ((x) + EPS_) : 1.f / ((x) - EPS_))

// ---------------------------------------------------------------------------
// prep: const2[c,k,e] = b_self[c,e] + it[c,k,:]·W_self[c,48:,e]
// (the b-independent part of the self embedding; 88 MFLOP total, 120 blocks)
// ---------------------------------------------------------------------------
__global__ __launch_bounds__(256) void prep(
    const float* __restrict__ init_trajs,  // [C,K,72]
    const float* __restrict__ W_self,      // [C,120,512]
    const float* __restrict__ b_self,      // [C,512]
    float*       __restrict__ c2)          // [C,K,512]
{
    const int tid = threadIdx.x;
    const int bid = blockIdx.x;            // = c*K + k, grid = 120
    const int c = bid / K_;
    const float* itr = init_trajs + (size_t)bid * DPRED;   // uniform address
    const float2* Wp = reinterpret_cast<const float2*>(
                           W_self + ((size_t)c * DSELF + DNEI) * E_) + tid;
    float2 acc = reinterpret_cast<const float2*>(b_self + (size_t)c * E_)[tid];
    #pragma unroll
    for (int j = 0; j < DPRED; ++j) {
        const float t  = itr[j];                 // wave-uniform
        const float2 w = Wp[(size_t)j * (E_ / 2)];
        acc.x += t * w.x; acc.y += t * w.y;
    }
    reinterpret_cast<float2*>(c2 + (size_t)bid * E_)[tid] = acc;
}

// ---------------------------------------------------------------------------
// self_fast: x[b,k,e] = obs[b,:48]·W_self[c,:48,e]  +  const2[c,k,e]
// GEMV (96 FMA/thread) then broadcast-add + store. Write-bound (~84 MB).
// ---------------------------------------------------------------------------
__global__ __launch_bounds__(256) void self_fast(
    const float* __restrict__ obs,      // [B,48]
    const float* __restrict__ W_self,   // [C,120,512]
    const int*   __restrict__ labels,   // [B]
    const float* __restrict__ c2,       // [C,K,512] (ws)
    float*       __restrict__ out)      // [B,K,512]
{
    const int b   = blockIdx.x;
    const int tid = threadIdx.x;
    const int c   = labels[b];

    const float*  ob = obs + (size_t)b * DNEI;
    const float2* Wp = reinterpret_cast<const float2*>(
                           W_self + (size_t)c * DSELF * E_) + tid;
    float ax = 0.f, ay = 0.f;
    #pragma unroll
    for (int j = 0; j < DNEI; ++j) {
        const float t  = ob[j];                      // wave-uniform
        const float2 w = Wp[(size_t)j * (E_ / 2)];
        ax += t * w.x; ay += t * w.y;
    }

    const float2* cp = reinterpret_cast<const float2*>(
                           c2 + (size_t)c * K_ * E_) + tid;
    float2* op = reinterpret_cast<float2*>(out + (size_t)b * K_ * E_) + tid;
    #pragma unroll
    for (int k = 0; k < K_; ++k) {
        const float2 v = cp[(size_t)k * (E_ / 2)];
        float2 o; o.x = ax + v.x; o.y = ay + v.y;
        op[(size_t)k * (E_ / 2)] = o;
    }
}

// ---------------------------------------------------------------------------
// nei_rl: round-5 structure (verified correct) with the register demotion
// FIXED: all per-thread state lives in NAMED float4 registers (r0..r11 row,
// wl0..wl11 / wh0..wh11 weight columns) with compile-time element access
// only — no indexed arrays, so the allocator cannot demote to scratch
// (rule: runtime-indexable aggregates go to scratch; named scalars don't).
// Row broadcast via v_readlane (reg static, lane index = uniform loop var ->
// SGPR). Zero LDS traffic, zero scalar-mem loads in the hot loop.
// Model: 64 rows x (48 readlane + 96 fmac) x 2cyc ~= 18.4k cyc/wave.
// ---------------------------------------------------------------------------
__global__ __launch_bounds__(256, 2) void nei_rl(
    const float* __restrict__ neis,    // [B,64,48]
    const float* __restrict__ W_nei,   // [C+1,48,512]
    const float* __restrict__ b_nei,   // [C+1,512]
    const int*   __restrict__ labels,  // [B,64]
    float*       __restrict__ out)     // [B,64,512]
{
    const int b    = blockIdx.x;
    const int tid  = threadIdx.x;
    const int lane = tid & 63;

    // --- my row (row `lane` of batch b), transformed, in named registers ---
    const float4* src = reinterpret_cast<const float4*>(
                            neis + (size_t)b * N_ * DNEI);
    float4 r0, r1, r2, r3, r4, r5, r6, r7, r8, r9, r10, r11;
#define LOADR(i) { const float4 v = src[lane * (DNEI / 4) + (i)]; \
    r##i = make_float4(TRF(v.x), TRF(v.y), TRF(v.z), TRF(v.w)); }
    LOADR(0) LOADR(1) LOADR(2)  LOADR(3)
    LOADR(4) LOADR(5) LOADR(6)  LOADR(7)
    LOADR(8) LOADR(9) LOADR(10) LOADR(11)
#undef LOADR

    const int myLab = labels[b * N_ + lane];

    float4 wl0, wl1, wl2, wl3, wl4, wl5, wl6, wl7, wl8, wl9, wl10, wl11;
    float4 wh0, wh1, wh2, wh3, wh4, wh5, wh6, wh7, wh8, wh9, wh10, wh11;

    for (int c = 0; c < C_ + 1; ++c) {
        const float2* Wp = reinterpret_cast<const float2*>(
                               W_nei + (size_t)c * DNEI * E_) + tid;
        // wlq.{x,y,z,w} = W[c, 4q+{0..3}, 2*tid], whq = same for e=2*tid+1
#define LOADW(q) { \
    const float2 wa = Wp[(4 * (q) + 0) * (E_ / 2)]; \
    const float2 wb = Wp[(4 * (q) + 1) * (E_ / 2)]; \
    const float2 wc = Wp[(4 * (q) + 2) * (E_ / 2)]; \
    const float2 wd = Wp[(4 * (q) + 3) * (E_ / 2)]; \
    wl##q = make_float4(wa.x, wb.x, wc.x, wd.x); \
    wh##q = make_float4(wa.y, wb.y, wc.y, wd.y); }
        LOADW(0) LOADW(1) LOADW(2)  LOADW(3)
        LOADW(4) LOADW(5) LOADW(6)  LOADW(7)
        LOADW(8) LOADW(9) LOADW(10) LOADW(11)
#undef LOADW
        const float2 bs = reinterpret_cast<const float2*>(
                              b_nei + (size_t)c * E_)[tid];

        for (int n = 0; n < N_; ++n) {
            const int labn = __builtin_amdgcn_readlane(myLab, n);  // SGPR
            if (labn != c) continue;     // scalar (wave-uniform) branch

            float a0 = bs.x, a1 = bs.y, a2 = 0.f, a3 = 0.f;
#define RLF(x) __int_as_float(__builtin_amdgcn_readlane(__float_as_int(x), n))
#define STEP(q) { \
    const float t0 = RLF(r##q.x), t1 = RLF(r##q.y); \
    const float t2 = RLF(r##q.z), t3 = RLF(r##q.w); \
    a0 += t0 * wl##q.x; a1 += t0 * wh##q.x; \
    a2 += t1 * wl##q.y; a3 += t1 * wh##q.y; \
    a0 += t2 * wl##q.z; a1 += t2 * wh##q.z; \
    a2 += t3 * wl##q.w; a3 += t3 * wh##q.w; }
            STEP(0) STEP(1) STEP(2)  STEP(3)
            STEP(4) STEP(5) STEP(6)  STEP(7)
            STEP(8) STEP(9) STEP(10) STEP(11)
#undef STEP
#undef RLF
            float2 o; o.x = a0 + a2; o.y = a1 + a3;
            reinterpret_cast<float2*>(out + ((size_t)b * N_ + n) * E_)[tid] = o;
        }
    }
}

// ---------------------------------------------------------------------------
// Fallback for the self path (round-0 verified) — only if d_ws is too small
// for const2 (240 KB). nei_rl needs no workspace.
// ---------------------------------------------------------------------------
__global__ __launch_bounds__(256) void self_embed_fb(
    const float* __restrict__ obs,
    const float* __restrict__ init_trajs,
    const float* __restrict__ W_self,
    const float* __restrict__ b_self,
    const int*   __restrict__ labels,
    float*       __restrict__ out)
{
    const int b   = blockIdx.x;
    const int tid = threadIdx.x;
    const int c   = labels[b];

    __shared__ __align__(16) float traj[DSELF * K_];

    for (int idx = tid; idx < DSELF * K_; idx += 256) {
        const int j = idx / K_;
        const int k = idx - j * K_;
        float v;
        if (j < DNEI) v = obs[b * DNEI + j];
        else          v = init_trajs[(c * K_ + k) * DPRED + (j - DNEI)];
        traj[idx] = v;
    }
    __syncthreads();

    float acc[K_][2];
    #pragma unroll
    for (int k = 0; k < K_; ++k) { acc[k][0] = 0.f; acc[k][1] = 0.f; }

    const float2* Wp = reinterpret_cast<const float2*>(W_self + (size_t)c * DSELF * E_) + tid;

    for (int j = 0; j < DSELF; ++j) {
        const float2 w  = Wp[j * (E_ / 2)];
        const float4* tp = reinterpret_cast<const float4*>(&traj[j * K_]);
        #pragma unroll
        for (int q = 0; q < 5; ++q) {
            const float4 t4 = tp[q];
            acc[q * 4 + 0][0] += t4.x * w.x; acc[q * 4 + 0][1] += t4.x * w.y;
            acc[q * 4 + 1][0] += t4.y * w.x; acc[q * 4 + 1][1] += t4.y * w.y;
            acc[q * 4 + 2][0] += t4.z * w.x; acc[q * 4 + 2][1] += t4.z * w.y;
            acc[q * 4 + 3][0] += t4.w * w.x; acc[q * 4 + 3][1] += t4.w * w.y;
        }
    }

    const float2 bs = reinterpret_cast<const float2*>(b_self + c * E_)[tid];
    #pragma unroll
    for (int k = 0; k < K_; ++k) {
        float2 o;
        o.x = acc[k][0] + bs.x;
        o.y = acc[k][1] + bs.y;
        reinterpret_cast<float2*>(out + (size_t)(b * K_ + k) * E_)[tid] = o;
    }
}

extern "C" void kernel_launch(void* const* d_in, const int* in_sizes, int n_in,
                              void* d_out, int out_size, void* d_ws, size_t ws_size,
                              hipStream_t stream) {
    const float* obs  = (const float*)d_in[0];
    const float* neis = (const float*)d_in[1];
    const float* it   = (const float*)d_in[2];
    const float* Ws   = (const float*)d_in[3];
    const float* bs   = (const float*)d_in[4];
    const float* Wn   = (const float*)d_in[5];
    const float* bn   = (const float*)d_in[6];
    const int* sl = (const int*)d_in[7];
    const int* nl = (const int*)d_in[8];

    float* out_x = (float*)d_out;                        // [B,K,E]
    float* out_n = out_x + (size_t)B_ * K_ * E_;         // [B,N,E]

    // neighbor path: no workspace needed
    nei_rl<<<dim3(B_), dim3(256), 0, stream>>>(neis, Wn, bn, nl, out_n);

    // self path: const2 precompute in ws if available, else verified fallback
    if (d_ws != nullptr && ws_size >= WS_NEED) {
        float* c2 = (float*)d_ws;                        // [C,K,E]
        prep<<<dim3(C_ * K_), dim3(256), 0, stream>>>(it, Ws, bs, c2);
        self_fast<<<dim3(B_), dim3(256), 0, stream>>>(obs, Ws, sl, c2, out_x);
    } else {
        self_embed_fb<<<dim3(B_), dim3(256), 0, stream>>>(obs, it, Ws, bs, sl, out_x);
    }
}